// Round 4
// baseline (111.711 us; speedup 1.0000x reference)
//
#include <hip/hip_runtime.h>
#include <stdint.h>

// GateDotProductAttention: B=8,S=2048,D=256 fp32 in/out.
// prep: K -> bf16 swizzled LDS-image tiles, V -> V^T bf16 72B-stride tiles, W -> bf16 chunks (d_ws)
// attn: fused bidirectional flash attention, no-max softmax, j-split across wave halves,
//       cross-period pipeline PV(t-1) || QK(t) -> SM(t), fused gate GEMMs + blend.

typedef unsigned short u16;
typedef unsigned int u32;
typedef __attribute__((ext_vector_type(8))) short short8;
typedef __attribute__((ext_vector_type(4))) short short4v;
typedef __attribute__((ext_vector_type(4))) float f32x4;

#define B_ 8
#define S_ 2048
#define D_ 256
#define QB 64
#define NP 32            // periods, 64 j-rows each

#define LOG2E 1.44269504088896340736f
#define QSCALE (LOG2E/16.0f)   // fold 1/sqrt(256) and log2(e) into Q

#define KSWZ_OFF 0
#define VT_OFF   (8u<<20)
#define VT_BATCH 1179648u            // 32 periods * 36864
#define WBF_OFF  (VT_OFF + 8u*VT_BATCH)

// LDS map (attn): K dbuf [0,64K) ; V dbuf [64K, 64K+72K) ; P slots [137.7K?]
#define LDS_K  0
#define LDS_V  65536
#define LDS_P  139264          // 65536 + 73728
// epilogue reuse: mergeF @0, mergeB @65536, sums @139264, att image @ h*32768, W @65536+buf*32768

__device__ __forceinline__ u16 f2bf(float f) {
    union { float f; u32 u; } x; x.f = f;
    u32 u = x.u + 0x7fffu + ((x.u >> 16) & 1u);   // RNE
    return (u16)(u >> 16);
}
__device__ __forceinline__ short8 pack8(float4 a, float4 b) {
    short8 r;
    r[0] = (short)f2bf(a.x); r[1] = (short)f2bf(a.y);
    r[2] = (short)f2bf(a.z); r[3] = (short)f2bf(a.w);
    r[4] = (short)f2bf(b.x); r[5] = (short)f2bf(b.y);
    r[6] = (short)f2bf(b.z); r[7] = (short)f2bf(b.w);
    return r;
}
__device__ __forceinline__ f32x4 mfma16(short8 a, short8 b, f32x4 c) {
    return __builtin_amdgcn_mfma_f32_16x16x32_bf16(a, b, c, 0, 0, 0);
}
__device__ __forceinline__ void gload_lds(const void* g, void* lds) {
    __builtin_amdgcn_global_load_lds(
        (const __attribute__((address_space(1))) void*)g,
        (__attribute__((address_space(3))) void*)lds, 16, 0, 0);
}

// ---------------------------------------------------------------- prep ----
__global__ __launch_bounds__(256, 1)
void prep_kernel(const float* __restrict__ k, const float* __restrict__ v,
                 const float* __restrict__ w0, const float* __restrict__ w1,
                 const float* __restrict__ w2, const float* __restrict__ w3,
                 char* __restrict__ ws)
{
    const int tid = (int)threadIdx.x;
    const int bid = (int)blockIdx.x;

    if (bid < 512) {
        // ---- V transpose tile: (b, jt) -> V^T [256 d][32 j] bf16, 72B row stride
        __shared__ float vs[32][257];
        const int b = bid >> 6, jt = bid & 63;
        const float* vb = v + ((size_t)b * S_ + (size_t)jt * 32) * D_;
        const int j = tid >> 3, d0 = (tid & 7) * 32;
        #pragma unroll
        for (int i = 0; i < 8; ++i) {
            float4 x = *(const float4*)(vb + (size_t)j * D_ + d0 + i * 4);
            vs[j][d0 + i * 4 + 0] = x.x; vs[j][d0 + i * 4 + 1] = x.y;
            vs[j][d0 + i * 4 + 2] = x.z; vs[j][d0 + i * 4 + 3] = x.w;
        }
        __syncthreads();
        char* ob = ws + VT_OFF + (size_t)b * VT_BATCH + (size_t)(jt >> 1) * 36864
                   + (size_t)(jt & 1) * 18432 + (size_t)tid * 72;
        short8 o[4];
        #pragma unroll
        for (int jj = 0; jj < 32; ++jj) o[jj >> 3][jj & 7] = (short)f2bf(vs[jj][tid]);
        #pragma unroll
        for (int i = 0; i < 4; ++i) *(short8*)(ob + i * 16) = o[i];
    } else if (bid < 1024) {
        // ---- K tile -> swizzled bf16 LDS image: row r, byte = r*512 + ((cg*16) ^ ((r&7)<<4))
        const int t = bid - 512, b = t >> 6, jt = t & 63;
        const float* kb = k + ((size_t)b * S_ + (size_t)jt * 32) * D_;
        char* ob = ws + KSWZ_OFF + (size_t)(b * 64 + jt) * 16384;
        #pragma unroll
        for (int it = 0; it < 4; ++it) {
            int gi = tid + it * 256;
            int r = gi >> 5, cg = gi & 31;
            float4 x0 = *(const float4*)(kb + (size_t)r * D_ + cg * 8);
            float4 x1 = *(const float4*)(kb + (size_t)r * D_ + cg * 8 + 4);
            *(short8*)(ob + r * 512 + ((cg * 16) ^ ((r & 7) << 4))) = pack8(x0, x1);
        }
    } else {
        // ---- W slice (m, db): 16 rows x 256 cols -> swizzled bf16, chunk order (db*4+m)
        const int t = bid - 1024, m = t >> 4, db = t & 15;
        const float* wsrc = (m == 0 ? w0 : m == 1 ? w1 : m == 2 ? w2 : w3)
                            + (size_t)(db * 16) * D_;
        char* ob = ws + WBF_OFF + (size_t)(db * 4 + m) * 8192;
        #pragma unroll
        for (int it = 0; it < 2; ++it) {
            int gi = tid + it * 256;
            int r = gi >> 5, cg = gi & 31;
            float4 x0 = *(const float4*)(wsrc + (size_t)r * D_ + cg * 8);
            float4 x1 = *(const float4*)(wsrc + (size_t)r * D_ + cg * 8 + 4);
            *(short8*)(ob + r * 512 + ((cg * 16) ^ ((r & 7) << 4))) = pack8(x0, x1);
        }
    }
}

// ---------------------------------------------------------------- attn ----
// PV for one staged P slot + V half-tile (72B-stride rows, b64 pairs, conflict-free)
#define PV_DO(pslot, vptr, accD, accS)                                         \
    {                                                                          \
        const u16* pp_ = (pslot);                                              \
        short4v plo_ = *(const short4v*)(pp_ + c * 36 + g * 8);                \
        short4v phi_ = *(const short4v*)(pp_ + c * 36 + g * 8 + 4);            \
        short8 pa_ = __builtin_shufflevector(plo_, phi_, 0,1,2,3,4,5,6,7);     \
        __builtin_amdgcn_s_setprio(1);                                         \
        accS = mfma16(pa_, onesb, accS);                                       \
        _Pragma("unroll")                                                      \
        for (int db = 0; db < 16; ++db) {                                      \
            const char* vp_ = (vptr) + (db * 16 + c) * 72 + g * 16;            \
            short4v vlo_ = *(const short4v*)(vp_);                             \
            short4v vhi_ = *(const short4v*)(vp_ + 8);                         \
            short8 vb_ = __builtin_shufflevector(vlo_, vhi_, 0,1,2,3,4,5,6,7); \
            accD[db] = mfma16(pa_, vb_, accD[db]);                             \
        }                                                                      \
        __builtin_amdgcn_s_setprio(0);                                         \
    }

__global__ __launch_bounds__(512, 2)
void attn_kernel(const float* __restrict__ q, const char* __restrict__ kswz,
                 const char* __restrict__ vt, const char* __restrict__ wbf,
                 const float* __restrict__ v,
                 const float* __restrict__ bo0, const float* __restrict__ bo1,
                 float* __restrict__ out)
{
    __shared__ char smem[157696];

    const int tid = (int)threadIdx.x;
    const int wv = tid >> 6, lane = tid & 63;
    const int h = wv >> 2, wl = wv & 3;
    const int g = lane >> 4, c = lane & 15;
    const int bid = (int)blockIdx.x;
    const int b = bid & 7, qi = bid >> 3;
    const int q0 = qi * QB;
    const int r0 = q0 + wl * 16;
    const int dt = r0 >> 5;             // diagonal 32-j-block index for this wave's rows

    u16* pwave = (u16*)(smem + LDS_P) + wv * 1152;   // 2 slots x 576 u16 (16 rows x 36)

    const char* kbaseg = kswz + (size_t)b * (64 * 16384);
    const char* vbaseg = vt + (size_t)b * VT_BATCH;

    // Q A-frags (pre-scaled)
    short8 qf[8];
    {
        const float* qp = q + ((size_t)b * S_ + (size_t)(r0 + c)) * D_;
        #pragma unroll
        for (int ks = 0; ks < 8; ++ks) {
            float4 a = *(const float4*)(qp + ks * 32 + g * 8);
            float4 d = *(const float4*)(qp + ks * 32 + g * 8 + 4);
            a.x *= QSCALE; a.y *= QSCALE; a.z *= QSCALE; a.w *= QSCALE;
            d.x *= QSCALE; d.y *= QSCALE; d.z *= QSCALE; d.w *= QSCALE;
            qf[ks] = pack8(a, d);
        }
    }

    short8 onesb;
    #pragma unroll
    for (int i = 0; i < 8; ++i) onesb[i] = (c == 0) ? (short)0x3F80 : (short)0;

    const f32x4 zero4 = {0.f, 0.f, 0.f, 0.f};
    f32x4 accF[16], accB[16], accSF = zero4, accSB = zero4;
    #pragma unroll
    for (int i = 0; i < 16; ++i) { accF[i] = zero4; accB[i] = zero4; }

    #define STAGE_K(t, buf)                                                    \
        {                                                                      \
            const char* kg_ = kbaseg + (size_t)(t) * 32768;                    \
            _Pragma("unroll")                                                  \
            for (int i = 0; i < 4; ++i) {                                      \
                int off = i * 8192 + wv * 1024;                                \
                gload_lds(kg_ + off + lane * 16, smem + LDS_K + (buf) * 32768 + off); \
            }                                                                  \
        }
    #define STAGE_V(t, buf)                                                    \
        {                                                                      \
            const char* vg_ = vbaseg + (size_t)(t) * 36864;                    \
            _Pragma("unroll")                                                  \
            for (int i = 0; i < 4; ++i) {                                      \
                int off = i * 8192 + wv * 1024;                                \
                gload_lds(vg_ + off + lane * 16, smem + LDS_V + (buf) * 36864 + off); \
            }                                                                  \
            if (wv < 4)                                                        \
                gload_lds(vg_ + 32768 + wv * 1024 + lane * 16,                 \
                          smem + LDS_V + (buf) * 36864 + 32768 + wv * 1024);   \
        }

    STAGE_K(0, 0);
    __syncthreads();

    const int swz = (c & 7) << 4;

    #pragma unroll 1
    for (int t = 0; t < NP; ++t) {
        const int cur = t & 1;
        if (t + 1 < NP) STAGE_K(t + 1, cur ^ 1);
        STAGE_V(t, cur);

        // ---- PV(t-1) (independent of QK(t))
        if (t > 0) {
            const int tp = t - 1, sp = tp & 1, jwp = 2 * tp + h;
            const u16* pP = pwave + sp * 576;
            const char* vP = smem + LDS_V + sp * 36864 + h * 18432;
            if (jwp < dt) { PV_DO(pP, vP, accB, accSB); }
            else if (jwp > dt) { PV_DO(pP, vP, accF, accSF); }
            else { PV_DO(pP, vP, accB, accSB);
                   PV_DO(pwave + (sp ^ 1) * 576, vP, accF, accSF); }
        }

        // ---- QK(t)
        const char* kcur = smem + LDS_K + cur * 32768 + h * 16384;
        f32x4 sc0 = zero4, sc1 = zero4;
        __builtin_amdgcn_s_setprio(1);
        #pragma unroll
        for (int ks = 0; ks < 8; ++ks) {
            int inner = (ks * 64 + g * 16) ^ swz;
            short8 kb0 = *(const short8*)(kcur + c * 512 + inner);
            short8 kb1 = *(const short8*)(kcur + (16 + c) * 512 + inner);
            sc0 = mfma16(qf[ks], kb0, sc0);
            sc1 = mfma16(qf[ks], kb1, sc1);
        }
        __builtin_amdgcn_s_setprio(0);

        // ---- SM(t): exp2 + (diag-only) masking, write P slot(s)
        const int jw = 2 * t + h, j0 = jw * 32;
        u16* pc = pwave + cur * 576;
        if (jw == dt) {
            u16* pf = pwave + (cur ^ 1) * 576;
            #pragma unroll
            for (int r = 0; r < 4; ++r) {
                int row = g * 4 + r, qq = r0 + row;
                float e0 = exp2f(sc0[r]), e1 = exp2f(sc1[r]);
                pc[row * 36 + c]      = f2bf((j0 + c) <= qq ? e0 : 0.0f);
                pc[row * 36 + 16 + c] = f2bf((j0 + 16 + c) <= qq ? e1 : 0.0f);
                pf[row * 36 + c]      = f2bf((j0 + c) >= qq ? e0 : 0.0f);
                pf[row * 36 + 16 + c] = f2bf((j0 + 16 + c) >= qq ? e1 : 0.0f);
            }
        } else {
            #pragma unroll
            for (int r = 0; r < 4; ++r) {
                int row = g * 4 + r;
                pc[row * 36 + c]      = f2bf(exp2f(sc0[r]));
                pc[row * 36 + 16 + c] = f2bf(exp2f(sc1[r]));
            }
        }
        __syncthreads();
    }

    // ---- final PV (t = NP-1)
    {
        const int tp = NP - 1, sp = tp & 1, jwp = 2 * tp + h;
        const u16* pP = pwave + sp * 576;
        const char* vP = smem + LDS_V + sp * 36864 + h * 18432;
        if (jwp < dt) { PV_DO(pP, vP, accB, accSB); }
        else if (jwp > dt) { PV_DO(pP, vP, accF, accSF); }
        else { PV_DO(pP, vP, accB, accSB);
               PV_DO(pwave + (sp ^ 1) * 576, vP, accF, accSF); }
    }
    __syncthreads();

    // ---- epilogue: merge halves, then fused gate ----
    float* sumsA = (float*)(smem + LDS_P);          // sF partial from half1 (64)
    float* sumsB = (float*)(smem + LDS_P + 256);    // sB partial from half0 (64)

    // P0: exchange partials (half1 acc-F -> [0,64K), half0 acc-B -> [64K,128K))
    if (h == 1) {
        float* dst = (float*)smem + wl * 4096;
        #pragma unroll
        for (int db = 0; db < 16; ++db)
            #pragma unroll
            for (int r = 0; r < 4; ++r)
                dst[(g * 4 + r) * 256 + db * 16 + c] = accF[db][r];
        if (c == 0) {
            #pragma unroll
            for (int r = 0; r < 4; ++r) sumsA[wl * 16 + g * 4 + r] = accSF[r];
        }
    } else {
        float* dst = (float*)(smem + LDS_V) + wl * 4096;
        #pragma unroll
        for (int db = 0; db < 16; ++db)
            #pragma unroll
            for (int r = 0; r < 4; ++r)
                dst[(g * 4 + r) * 256 + db * 16 + c] = accB[db][r];
        if (c == 0) {
            #pragma unroll
            for (int r = 0; r < 4; ++r) sumsB[wl * 16 + g * 4 + r] = accSB[r];
        }
    }
    __syncthreads();

    // P1: merge + normalize. half0 owns fw rows, half1 owns bw rows.
    f32x4 merged[16];
    if (h == 0) {
        const float* src = (const float*)smem + wl * 4096;
        float rs[4];
        #pragma unroll
        for (int r = 0; r < 4; ++r) {
            float so = __shfl(accSF[r], lane & 48);
            rs[r] = 1.0f / (so + sumsA[wl * 16 + g * 4 + r]);
        }
        #pragma unroll
        for (int db = 0; db < 16; ++db)
            #pragma unroll
            for (int r = 0; r < 4; ++r)
                merged[db][r] = (accF[db][r] + src[(g * 4 + r) * 256 + db * 16 + c]) * rs[r];
    } else {
        const float* src = (const float*)(smem + LDS_V) + wl * 4096;
        float rs[4];
        #pragma unroll
        for (int r = 0; r < 4; ++r) {
            float so = __shfl(accSB[r], lane & 48);
            rs[r] = 1.0f / (so + sumsB[wl * 16 + g * 4 + r]);
        }
        #pragma unroll
        for (int db = 0; db < 16; ++db)
            #pragma unroll
            for (int r = 0; r < 4; ++r)
                merged[db][r] = (accB[db][r] + src[(g * 4 + r) * 256 + db * 16 + c]) * rs[r];
    }
    __syncthreads();

    // P2: write att_v bf16 swizzled image (h0: fw @[0,32K), h1: bw @[32K,64K)) + stage W chunk 0
    {
        char* imgb = smem + h * 32768;
        #pragma unroll
        for (int db = 0; db < 16; ++db)
            #pragma unroll
            for (int r = 0; r < 4; ++r) {
                int lr = wl * 16 + g * 4 + r;
                int cb = (db * 16 + c) * 2;
                *(u16*)(imgb + lr * 512 + (cb ^ ((lr & 7) << 4))) = f2bf(merged[db][r]);
            }
    }
    #define WSTAGE(db, buf)                                                    \
        {                                                                      \
            const char* gsrc = wbf + (size_t)(db) * 32768;                     \
            _Pragma("unroll")                                                  \
            for (int i = 0; i < 4; ++i) {                                      \
                int off = i * 8192 + wv * 1024;                                \
                gload_lds(gsrc + off + lane * 16,                              \
                          smem + LDS_V + (buf) * 32768 + off);                 \
            }                                                                  \
        }
    WSTAGE(0, 0);
    __syncthreads();

    // P3: A-frags for own direction (att image) and v (global)
    short8 af[8], vf[8];
    {
        const char* imgb = smem + h * 32768;
        int lr = wl * 16 + c;
        #pragma unroll
        for (int ks = 0; ks < 8; ++ks) {
            int inner = (ks * 64 + g * 16) ^ swz;
            af[ks] = *(const short8*)(imgb + lr * 512 + inner);
        }
        const float* vp = v + ((size_t)b * S_ + (size_t)(r0 + c)) * D_;
        #pragma unroll
        for (int ks = 0; ks < 8; ++ks) {
            float4 a = *(const float4*)(vp + ks * 32 + g * 8);
            float4 d = *(const float4*)(vp + ks * 32 + g * 8 + 4);
            vf[ks] = pack8(a, d);
        }
    }

    // db loop: gate GEMM (own direction) + blend + store
    const float* bias = (h == 0) ? bo0 : bo1;
    const float* vrow = v + ((size_t)b * S_ + (size_t)r0) * D_;
    float* ob = out + ((size_t)b * S_ + (size_t)r0) * 512 + h * 256;
    #pragma unroll
    for (int db = 0; db < 16; ++db) {
        const int cu2 = db & 1;
        if (db + 1 < 16) WSTAGE(db + 1, cu2 ^ 1);

        float bb = bias[db * 16 + c];
        f32x4 a = {bb, bb, bb, bb};
        const char* wc = smem + LDS_V + cu2 * 32768 + h * 16384;
        __builtin_amdgcn_s_setprio(1);
        #pragma unroll
        for (int ks = 0; ks < 8; ++ks) {
            int inner = (ks * 64 + g * 16) ^ swz;
            short8 wi = *(const short8*)(wc + c * 512 + inner);
            short8 wo = *(const short8*)(wc + 8192 + c * 512 + inner);
            a = mfma16(vf[ks], wi, a);
            a = mfma16(af[ks], wo, a);
        }
        __builtin_amdgcn_s_setprio(0);

        #pragma unroll
        for (int r = 0; r < 4; ++r) {
            int row = g * 4 + r;
            float vv = vrow[(size_t)row * D_ + db * 16 + c];
            float gate = 1.0f / (1.0f + exp2f(-a[r] * LOG2E));
            float m = merged[db][r];
            ob[(size_t)row * 512 + db * 16 + c] = gate * m + (1.0f - gate) * vv;
        }
        __syncthreads();
    }
}

extern "C" void kernel_launch(void* const* d_in, const int* in_sizes, int n_in,
                              void* d_out, int out_size, void* d_ws, size_t ws_size,
                              hipStream_t stream)
{
    const float* q   = (const float*)d_in[0];
    const float* k   = (const float*)d_in[1];
    const float* v   = (const float*)d_in[2];
    const float* Wi0 = (const float*)d_in[3];
    const float* Wi1 = (const float*)d_in[4];
    const float* Wo0 = (const float*)d_in[5];
    const float* Wo1 = (const float*)d_in[6];
    const float* bo0 = (const float*)d_in[7];
    const float* bo1 = (const float*)d_in[8];
    float* out = (float*)d_out;
    char* ws = (char*)d_ws;
    (void)in_sizes; (void)n_in; (void)ws_size; (void)out_size;

    // prep: K-swz [0,8MB), V^T 72B-stride [8MB,17MB), W-bf16 chunks [~17MB,+512KB)
    prep_kernel<<<dim3(1088), dim3(256), 0, stream>>>(k, v, Wi0, Wo0, Wi1, Wo1, ws);
    attn_kernel<<<dim3(256), dim3(512), 0, stream>>>(q, ws + KSWZ_OFF, ws + VT_OFF,
                                                     ws + WBF_OFF, v, bo0, bo1, out);
}

// Round 5
// 103.408 us; speedup vs baseline: 1.0803x; 1.0803x over previous
//
#include <hip/hip_runtime.h>
#include <stdint.h>

// GateDotProductAttention: B=8,S=2048,D=256 fp32 in/out.
// prep: K -> bf16 swizzled LDS-image tiles, V -> V^T bf16 80B-stride tiles, W -> bf16 chunks (d_ws)
// attn: fused bidirectional flash attention (no-max softmax, j-split across wave halves,
//       2 waves/SIMD) + fused gate GEMMs + sigmoid blend. Single out write.
// R5 = R3 structure (no cross-period pipeline; register-neutral) + 80B-padded V^T
//      (PV ds_read_b128 2-way aliased = free, vs 8-way at 64B stride).

typedef unsigned short u16;
typedef unsigned int u32;
typedef __attribute__((ext_vector_type(8))) short short8;
typedef __attribute__((ext_vector_type(4))) float f32x4;

#define B_ 8
#define S_ 2048
#define D_ 256
#define QB 64
#define NP 32            // periods, 64 j-rows each

#define LOG2E 1.44269504088896340736f
#define QSCALE (LOG2E/16.0f)   // fold 1/sqrt(256) and log2(e) into Q

#define KSWZ_OFF 0
#define VT_OFF   (8u<<20)
#define VT_PERIOD 40960u               // 2 x (256 rows x 80B)
#define VT_BATCH (32u*VT_PERIOD)       // 1,310,720
#define WBF_OFF  (VT_OFF + 8u*VT_BATCH)

// LDS map (attn): K dbuf [0,64K) ; V dbuf [64K,64K+80K) ; P [147456,157696)
#define LDS_K  0
#define LDS_V  65536
#define LDS_P  147456
// epilogue reuse: merge-F @0, merge-B @65536, sums @LDS_P, att image @ h*32768, W @65536+buf*32768

__device__ __forceinline__ u16 f2bf(float f) {
    union { float f; u32 u; } x; x.f = f;
    u32 u = x.u + 0x7fffu + ((x.u >> 16) & 1u);   // RNE
    return (u16)(u >> 16);
}
__device__ __forceinline__ short8 pack8(float4 a, float4 b) {
    short8 r;
    r[0] = (short)f2bf(a.x); r[1] = (short)f2bf(a.y);
    r[2] = (short)f2bf(a.z); r[3] = (short)f2bf(a.w);
    r[4] = (short)f2bf(b.x); r[5] = (short)f2bf(b.y);
    r[6] = (short)f2bf(b.z); r[7] = (short)f2bf(b.w);
    return r;
}
__device__ __forceinline__ f32x4 mfma16(short8 a, short8 b, f32x4 c) {
    return __builtin_amdgcn_mfma_f32_16x16x32_bf16(a, b, c, 0, 0, 0);
}
__device__ __forceinline__ void gload_lds(const void* g, void* lds) {
    __builtin_amdgcn_global_load_lds(
        (const __attribute__((address_space(1))) void*)g,
        (__attribute__((address_space(3))) void*)lds, 16, 0, 0);
}

// ---------------------------------------------------------------- prep ----
__global__ __launch_bounds__(256, 1)
void prep_kernel(const float* __restrict__ k, const float* __restrict__ v,
                 const float* __restrict__ w0, const float* __restrict__ w1,
                 const float* __restrict__ w2, const float* __restrict__ w3,
                 char* __restrict__ ws)
{
    const int tid = (int)threadIdx.x;
    const int bid = (int)blockIdx.x;

    if (bid < 512) {
        // ---- V transpose tile: (b, jt) -> V^T [256 d][32 j] bf16, 80B row stride
        __shared__ float vs[32][257];
        const int b = bid >> 6, jt = bid & 63;
        const float* vb = v + ((size_t)b * S_ + (size_t)jt * 32) * D_;
        const int j = tid >> 3, d0 = (tid & 7) * 32;
        #pragma unroll
        for (int i = 0; i < 8; ++i) {
            float4 x = *(const float4*)(vb + (size_t)j * D_ + d0 + i * 4);
            vs[j][d0 + i * 4 + 0] = x.x; vs[j][d0 + i * 4 + 1] = x.y;
            vs[j][d0 + i * 4 + 2] = x.z; vs[j][d0 + i * 4 + 3] = x.w;
        }
        __syncthreads();
        char* ob = ws + VT_OFF + (size_t)b * VT_BATCH + (size_t)(jt >> 1) * VT_PERIOD
                   + (size_t)(jt & 1) * 20480 + (size_t)tid * 80;
        short8 o[4];
        #pragma unroll
        for (int jj = 0; jj < 32; ++jj) o[jj >> 3][jj & 7] = (short)f2bf(vs[jj][tid]);
        #pragma unroll
        for (int i = 0; i < 4; ++i) *(short8*)(ob + i * 16) = o[i];
    } else if (bid < 1024) {
        // ---- K tile -> swizzled bf16 LDS image: row r, byte = r*512 + ((cg*16) ^ ((r&7)<<4))
        const int t = bid - 512, b = t >> 6, jt = t & 63;
        const float* kb = k + ((size_t)b * S_ + (size_t)jt * 32) * D_;
        char* ob = ws + KSWZ_OFF + (size_t)(b * 64 + jt) * 16384;
        #pragma unroll
        for (int it = 0; it < 4; ++it) {
            int gi = tid + it * 256;
            int r = gi >> 5, cg = gi & 31;
            float4 x0 = *(const float4*)(kb + (size_t)r * D_ + cg * 8);
            float4 x1 = *(const float4*)(kb + (size_t)r * D_ + cg * 8 + 4);
            *(short8*)(ob + r * 512 + ((cg * 16) ^ ((r & 7) << 4))) = pack8(x0, x1);
        }
    } else {
        // ---- W slice (m, db): 16 rows x 256 cols -> swizzled bf16, chunk order (db*4+m)
        const int t = bid - 1024, m = t >> 4, db = t & 15;
        const float* wsrc = (m == 0 ? w0 : m == 1 ? w1 : m == 2 ? w2 : w3)
                            + (size_t)(db * 16) * D_;
        char* ob = ws + WBF_OFF + (size_t)(db * 4 + m) * 8192;
        #pragma unroll
        for (int it = 0; it < 2; ++it) {
            int gi = tid + it * 256;
            int r = gi >> 5, cg = gi & 31;
            float4 x0 = *(const float4*)(wsrc + (size_t)r * D_ + cg * 8);
            float4 x1 = *(const float4*)(wsrc + (size_t)r * D_ + cg * 8 + 4);
            *(short8*)(ob + r * 512 + ((cg * 16) ^ ((r & 7) << 4))) = pack8(x0, x1);
        }
    }
}

// ---------------------------------------------------------------- attn ----
#define PV_TAIL(accD, accS)                                                    \
    {                                                                          \
        short8 pa = *(const short8*)&pw[c * 40 + g * 8];                       \
        __builtin_amdgcn_s_setprio(1);                                         \
        accS = mfma16(pa, onesb, accS);                                        \
        _Pragma("unroll")                                                      \
        for (int db = 0; db < 16; ++db) {                                      \
            short8 vb = *(const short8*)(vcur + (db * 16 + c) * 80 + g * 16);  \
            accD[db] = mfma16(pa, vb, accD[db]);                               \
        }                                                                      \
        __builtin_amdgcn_s_setprio(0);                                         \
    }

#define DO_FULL(accD, accS)                                                    \
    {                                                                          \
        _Pragma("unroll")                                                      \
        for (int r = 0; r < 4; ++r) {                                          \
            pw[(g * 4 + r) * 40 + c]      = f2bf(exp2f(sc0[r]));               \
            pw[(g * 4 + r) * 40 + 16 + c] = f2bf(exp2f(sc1[r]));               \
        }                                                                      \
        PV_TAIL(accD, accS)                                                    \
    }

#define DO_MASK(CMPOP, accD, accS)                                             \
    {                                                                          \
        _Pragma("unroll")                                                      \
        for (int r = 0; r < 4; ++r) {                                          \
            int qq = r0 + g * 4 + r;                                           \
            float e0 = ((j0 + c) CMPOP qq) ? exp2f(sc0[r]) : 0.0f;             \
            float e1 = ((j0 + 16 + c) CMPOP qq) ? exp2f(sc1[r]) : 0.0f;        \
            pw[(g * 4 + r) * 40 + c]      = f2bf(e0);                          \
            pw[(g * 4 + r) * 40 + 16 + c] = f2bf(e1);                          \
        }                                                                      \
        PV_TAIL(accD, accS)                                                    \
    }

__global__ __launch_bounds__(512, 2)
void attn_kernel(const float* __restrict__ q, const char* __restrict__ kswz,
                 const char* __restrict__ vt, const char* __restrict__ wbf,
                 const float* __restrict__ v,
                 const float* __restrict__ bo0, const float* __restrict__ bo1,
                 float* __restrict__ out)
{
    __shared__ char smem[157696];
    u16* pl = (u16*)(smem + LDS_P);

    const int tid = (int)threadIdx.x;
    const int wv = tid >> 6, lane = tid & 63;
    const int h = wv >> 2, wl = wv & 3;
    const int g = lane >> 4, c = lane & 15;
    const int bid = (int)blockIdx.x;
    const int b = bid & 7, qi = bid >> 3;
    const int q0 = qi * QB;
    const int r0 = q0 + wl * 16;            // global q row base of this wave
    const int dt = r0 >> 5;                 // diagonal 32-j-block index
    u16* pw = pl + wv * 640;

    const char* kbaseg = kswz + (size_t)b * (64 * 16384);
    const char* vbaseg = vt + (size_t)b * VT_BATCH;

    // Q A-frags (pre-scaled)
    short8 qf[8];
    {
        const float* qp = q + ((size_t)b * S_ + (size_t)(r0 + c)) * D_;
        #pragma unroll
        for (int ks = 0; ks < 8; ++ks) {
            float4 a = *(const float4*)(qp + ks * 32 + g * 8);
            float4 d = *(const float4*)(qp + ks * 32 + g * 8 + 4);
            a.x *= QSCALE; a.y *= QSCALE; a.z *= QSCALE; a.w *= QSCALE;
            d.x *= QSCALE; d.y *= QSCALE; d.z *= QSCALE; d.w *= QSCALE;
            qf[ks] = pack8(a, d);
        }
    }

    short8 onesb;
    #pragma unroll
    for (int i = 0; i < 8; ++i) onesb[i] = (c == 0) ? (short)0x3F80 : (short)0;

    const f32x4 zero4 = {0.f, 0.f, 0.f, 0.f};
    f32x4 accF[16], accB[16], accSF = zero4, accSB = zero4;
    #pragma unroll
    for (int i = 0; i < 16; ++i) { accF[i] = zero4; accB[i] = zero4; }

    // stage one 64-row period: 32KB K (4 rounds) + 40KB V^T (5 rounds)
    #define STAGE(t, buf)                                                      \
        {                                                                      \
            const char* kg_ = kbaseg + (size_t)(t) * 32768;                    \
            const char* vg_ = vbaseg + (size_t)(t) * VT_PERIOD;                \
            _Pragma("unroll")                                                  \
            for (int i = 0; i < 4; ++i) {                                      \
                int off = i * 8192 + wv * 1024;                                \
                gload_lds(kg_ + off + lane * 16, smem + LDS_K + (buf) * 32768 + off); \
            }                                                                  \
            _Pragma("unroll")                                                  \
            for (int i = 0; i < 5; ++i) {                                      \
                int off = i * 8192 + wv * 1024;                                \
                gload_lds(vg_ + off + lane * 16, smem + LDS_V + (buf) * 40960 + off); \
            }                                                                  \
        }

    STAGE(0, 0);
    __syncthreads();

    const int swz = (c & 7) << 4;

    #pragma unroll 1
    for (int t = 0; t < NP; ++t) {
        const int cur = t & 1;
        if (t + 1 < NP) STAGE(t + 1, cur ^ 1);

        const int jw = 2 * t + h;           // this wave's 32-j block index
        const int j0 = jw * 32;
        const char* kcur = smem + LDS_K + cur * 32768 + h * 16384;
        const char* vcur = smem + LDS_V + cur * 40960 + h * 20480;

        f32x4 sc0 = zero4, sc1 = zero4;
        __builtin_amdgcn_s_setprio(1);
        #pragma unroll
        for (int ks = 0; ks < 8; ++ks) {
            int inner = (ks * 64 + g * 16) ^ swz;
            short8 kb0 = *(const short8*)(kcur + c * 512 + inner);
            short8 kb1 = *(const short8*)(kcur + (16 + c) * 512 + inner);
            sc0 = mfma16(qf[ks], kb0, sc0);
            sc1 = mfma16(qf[ks], kb1, sc1);
        }
        __builtin_amdgcn_s_setprio(0);

        if (jw < dt) {
            DO_FULL(accB, accSB)
        } else if (jw > dt) {
            DO_FULL(accF, accSF)
        } else {
            DO_MASK(<=, accB, accSB)
            DO_MASK(>=, accF, accSF)
        }
        __syncthreads();
    }

    // ---- epilogue: merge halves, then fused gate ----
    float* sumsA = (float*)(smem + LDS_P);          // sF partial from half1 (64)
    float* sumsB = (float*)(smem + LDS_P + 256);    // sB partial from half0 (64)

    // P0: exchange partials (half1 acc-F -> [0,64K), half0 acc-B -> [64K,128K))
    if (h == 1) {
        float* dst = (float*)smem + wl * 4096;
        #pragma unroll
        for (int db = 0; db < 16; ++db)
            #pragma unroll
            for (int r = 0; r < 4; ++r)
                dst[(g * 4 + r) * 256 + db * 16 + c] = accF[db][r];
        if (c == 0) {
            #pragma unroll
            for (int r = 0; r < 4; ++r) sumsA[wl * 16 + g * 4 + r] = accSF[r];
        }
    } else {
        float* dst = (float*)(smem + LDS_V) + wl * 4096;
        #pragma unroll
        for (int db = 0; db < 16; ++db)
            #pragma unroll
            for (int r = 0; r < 4; ++r)
                dst[(g * 4 + r) * 256 + db * 16 + c] = accB[db][r];
        if (c == 0) {
            #pragma unroll
            for (int r = 0; r < 4; ++r) sumsB[wl * 16 + g * 4 + r] = accSB[r];
        }
    }
    __syncthreads();

    // P1: merge + normalize. half0 owns fw rows, half1 owns bw rows.
    f32x4 merged[16];
    if (h == 0) {
        const float* src = (const float*)smem + wl * 4096;
        float rs[4];
        #pragma unroll
        for (int r = 0; r < 4; ++r) {
            float so = __shfl(accSF[r], lane & 48);
            rs[r] = 1.0f / (so + sumsA[wl * 16 + g * 4 + r]);
        }
        #pragma unroll
        for (int db = 0; db < 16; ++db)
            #pragma unroll
            for (int r = 0; r < 4; ++r)
                merged[db][r] = (accF[db][r] + src[(g * 4 + r) * 256 + db * 16 + c]) * rs[r];
    } else {
        const float* src = (const float*)(smem + LDS_V) + wl * 4096;
        float rs[4];
        #pragma unroll
        for (int r = 0; r < 4; ++r) {
            float so = __shfl(accSB[r], lane & 48);
            rs[r] = 1.0f / (so + sumsB[wl * 16 + g * 4 + r]);
        }
        #pragma unroll
        for (int db = 0; db < 16; ++db)
            #pragma unroll
            for (int r = 0; r < 4; ++r)
                merged[db][r] = (accB[db][r] + src[(g * 4 + r) * 256 + db * 16 + c]) * rs[r];
    }
    __syncthreads();

    // P2: write att_v bf16 swizzled image (h0: fw @[0,32K), h1: bw @[32K,64K)) + stage W chunk 0
    {
        char* imgb = smem + h * 32768;
        #pragma unroll
        for (int db = 0; db < 16; ++db)
            #pragma unroll
            for (int r = 0; r < 4; ++r) {
                int lr = wl * 16 + g * 4 + r;
                int cb = (db * 16 + c) * 2;
                *(u16*)(imgb + lr * 512 + (cb ^ ((lr & 7) << 4))) = f2bf(merged[db][r]);
            }
    }
    #define WSTAGE(db, buf)                                                    \
        {                                                                      \
            const char* gsrc = wbf + (size_t)(db) * 32768;                     \
            _Pragma("unroll")                                                  \
            for (int i = 0; i < 4; ++i) {                                      \
                int off = i * 8192 + wv * 1024;                                \
                gload_lds(gsrc + off + lane * 16,                              \
                          smem + LDS_V + (buf) * 32768 + off);                 \
            }                                                                  \
        }
    WSTAGE(0, 0);
    __syncthreads();

    // P3: A-frags for own direction (att image) and v (global)
    short8 af[8], vf[8];
    {
        const char* imgb = smem + h * 32768;
        int lr = wl * 16 + c;
        #pragma unroll
        for (int ks = 0; ks < 8; ++ks) {
            int inner = (ks * 64 + g * 16) ^ swz;
            af[ks] = *(const short8*)(imgb + lr * 512 + inner);
        }
        const float* vp = v + ((size_t)b * S_ + (size_t)(r0 + c)) * D_;
        #pragma unroll
        for (int ks = 0; ks < 8; ++ks) {
            float4 a = *(const float4*)(vp + ks * 32 + g * 8);
            float4 d = *(const float4*)(vp + ks * 32 + g * 8 + 4);
            vf[ks] = pack8(a, d);
        }
    }

    // db loop: gate GEMM (own direction) + blend + store
    const float* bias = (h == 0) ? bo0 : bo1;
    const float* vrow = v + ((size_t)b * S_ + (size_t)r0) * D_;
    float* ob = out + ((size_t)b * S_ + (size_t)r0) * 512 + h * 256;
    #pragma unroll
    for (int db = 0; db < 16; ++db) {
        const int cu2 = db & 1;
        if (db + 1 < 16) WSTAGE(db + 1, cu2 ^ 1);

        float bb = bias[db * 16 + c];
        f32x4 a = {bb, bb, bb, bb};
        const char* wc = smem + LDS_V + cu2 * 32768 + h * 16384;
        __builtin_amdgcn_s_setprio(1);
        #pragma unroll
        for (int ks = 0; ks < 8; ++ks) {
            int inner = (ks * 64 + g * 16) ^ swz;
            short8 wi = *(const short8*)(wc + c * 512 + inner);
            short8 wo = *(const short8*)(wc + 8192 + c * 512 + inner);
            a = mfma16(vf[ks], wi, a);
            a = mfma16(af[ks], wo, a);
        }
        __builtin_amdgcn_s_setprio(0);

        #pragma unroll
        for (int r = 0; r < 4; ++r) {
            int row = g * 4 + r;
            float vv = vrow[(size_t)row * D_ + db * 16 + c];
            float gate = 1.0f / (1.0f + exp2f(-a[r] * LOG2E));
            float m = merged[db][r];
            ob[(size_t)row * 512 + db * 16 + c] = gate * m + (1.0f - gate) * vv;
        }
        __syncthreads();
    }
}

extern "C" void kernel_launch(void* const* d_in, const int* in_sizes, int n_in,
                              void* d_out, int out_size, void* d_ws, size_t ws_size,
                              hipStream_t stream)
{
    const float* q   = (const float*)d_in[0];
    const float* k   = (const float*)d_in[1];
    const float* v   = (const float*)d_in[2];
    const float* Wi0 = (const float*)d_in[3];
    const float* Wi1 = (const float*)d_in[4];
    const float* Wo0 = (const float*)d_in[5];
    const float* Wo1 = (const float*)d_in[6];
    const float* bo0 = (const float*)d_in[7];
    const float* bo1 = (const float*)d_in[8];
    float* out = (float*)d_out;
    char* ws = (char*)d_ws;
    (void)in_sizes; (void)n_in; (void)ws_size; (void)out_size;

    // prep: K-swz [0,8MB), V^T 80B-stride [8MB,18MB), W-bf16 chunks [18MB,+512KB)
    prep_kernel<<<dim3(1088), dim3(256), 0, stream>>>(k, v, Wi0, Wo0, Wi1, Wo1, ws);
    attn_kernel<<<dim3(256), dim3(512), 0, stream>>>(q, ws + KSWZ_OFF, ws + VT_OFF,
                                                     ws + WBF_OFF, v, bo0, bo1, out);
}